// Round 5
// baseline (31.345 us; speedup 1.0000x reference)
//
#include <hip/hip_runtime.h>
#include <hip/hip_bf16.h>

// Problem constants (from reference): B=16, S=512, H=768.
#define BB 16
#define SS 512
#define HH 768
#define H4 (HH / 4)    // 192 float4 per row
#define HS 64          // float4 columns per block (64 threads, 1 wave)
#define NHS (H4 / HS)  // 3 h-slices
#define TC 32          // tokens per chunk
#define NSC (SS / TC)  // 16 s-chunks

// Native clang vector type — __builtin_nontemporal_* requires it (HIP's
// float4 is a class and is rejected).
typedef float f32x4 __attribute__((ext_vector_type(4)));

// One wave per (b, h-slice, s-chunk). Register sliding window over the
// layer-summed rows m[t+1], m[t+2], m[t+3]; each row of hidden is loaded
// exactly once per block (plus a 3-row halo at chunk boundaries).
// Streaming: non-temporal loads/stores; spans broadcast via shfl.
__global__ __launch_bounds__(64) void span_pool_kernel(
    const float* __restrict__ hidden, const int* __restrict__ spans,
    const int* __restrict__ masks, float* __restrict__ out) {

    const int sc   = blockIdx.x;
    const int hs   = blockIdx.y;
    const int b    = blockIdx.z;
    const int lane = threadIdx.x;  // 0..63

    // mask_len[b] = sum(masks[b,:]) — fused per-block reduce (2 KB, cache-hot).
    int msum = 0;
    const int* mrow = masks + b * SS;
    #pragma unroll
    for (int i = 0; i < SS / 64; ++i) msum += mrow[lane + i * 64];
    #pragma unroll
    for (int off = 32; off; off >>= 1) msum += __shfl_down(msum, off, 64);
    const int ml = __shfl(msum, 0, 64);

    const int t0  = sc * TC;
    const int col = hs * HS + lane;              // this thread's float4 column
    const size_t LSTR = (size_t)BB * SS * H4;    // layer stride in float4

    // Coalesced span preload: lane i (i<TC) holds spans[b, t0+i].
    int myspan = 0;
    if (lane < TC) myspan = spans[b * SS + t0 + lane];

    const f32x4* hb = (const f32x4*)hidden + (size_t)b * SS * H4 + col;

    auto loadrow = [&](int j) {
        j = min(j, SS - 1);                      // clamped halo rows get weight 0
        const f32x4* p = hb + (size_t)j * H4;
        f32x4 a = __builtin_nontemporal_load(&p[0]);
        f32x4 c = __builtin_nontemporal_load(&p[LSTR]);
        f32x4 d = __builtin_nontemporal_load(&p[2 * LSTR]);
        f32x4 e = __builtin_nontemporal_load(&p[3 * LSTR]);
        return a + c + d + e;
    };

    f32x4 m1 = loadrow(t0 + 1);
    f32x4 m2 = loadrow(t0 + 2);
    f32x4 m3 = loadrow(t0 + 3);

    f32x4* orow = (f32x4*)out + ((size_t)b * SS + t0) * H4 + col;

    #pragma unroll 8
    for (int i = 0; i < TC; ++i) {
        const int t = t0 + i;
        f32x4 nxt = loadrow(t + 4);              // prefetch next window row
        const int span_i = __shfl(myspan, i, 64);
        const bool valid = (t >= 1) && (t < ml - 1);
        const int n = min(span_i, SS - 1 - t);   // 1..3 when valid
        const float w1 = valid ? 0.25f : 0.0f;
        const float w2 = (valid && n >= 2) ? 0.25f : 0.0f;
        const float w3 = (valid && n >= 3) ? 0.25f : 0.0f;
        f32x4 r = w1 * m1 + w2 * m2 + w3 * m3;
        __builtin_nontemporal_store(r, &orow[(size_t)i * H4]);
        m1 = m2; m2 = m3; m3 = nxt;
    }
}

extern "C" void kernel_launch(void* const* d_in, const int* in_sizes, int n_in,
                              void* d_out, int out_size, void* d_ws, size_t ws_size,
                              hipStream_t stream) {
    const float* hidden = (const float*)d_in[0];  // [4,B,S,H] f32
    const int* spans    = (const int*)d_in[1];    // [B,S] i32
    const int* masks    = (const int*)d_in[2];    // [B,S] i32
    float* out          = (float*)d_out;          // [B,S,H] f32

    dim3 grid(NSC, NHS, BB);  // 16 x 3 x 16 = 768 single-wave blocks
    span_pool_kernel<<<grid, dim3(64), 0, stream>>>(hidden, spans, masks, out);
}

// Round 6
// 24.980 us; speedup vs baseline: 1.2548x; 1.2548x over previous
//
#include <hip/hip_runtime.h>
#include <hip/hip_bf16.h>

// Problem constants (from reference): B=16, S=512, H=768.
#define BB 16
#define SS 512
#define HH 768
#define H4 (HH / 4)    // 192 float4 per row
#define HS 64          // float4 columns per block (64 threads, 1 wave)
#define NHS (H4 / HS)  // 3 h-slices
#define TC 32          // tokens per chunk
#define NSC (SS / TC)  // 16 s-chunks

typedef float f32x4 __attribute__((ext_vector_type(4)));

// One wave per (b, h-slice, s-chunk). Register sliding window over the
// layer-summed rows m[t+1], m[t+2], m[t+3]; each row of hidden is loaded
// exactly once per block (plus a 3-row halo at chunk boundaries).
// R5: back to R2 structure (unroll 4, cached loads); span preload + shfl
// broadcast; initial window loads issued before the mask reduce.
__global__ __launch_bounds__(64) void span_pool_kernel(
    const float* __restrict__ hidden, const int* __restrict__ spans,
    const int* __restrict__ masks, float* __restrict__ out) {

    const int sc   = blockIdx.x;
    const int hs   = blockIdx.y;
    const int b    = blockIdx.z;
    const int lane = threadIdx.x;  // 0..63

    const int t0  = sc * TC;
    const int col = hs * HS + lane;              // this thread's float4 column
    const size_t LSTR = (size_t)BB * SS * H4;    // layer stride in float4

    const f32x4* hb = (const f32x4*)hidden + (size_t)b * SS * H4 + col;

    auto loadrow = [&](int j) {
        j = min(j, SS - 1);                      // clamped halo rows get weight 0
        const f32x4* p = hb + (size_t)j * H4;
        f32x4 a = p[0], c = p[LSTR], d = p[2 * LSTR], e = p[3 * LSTR];
        return a + c + d + e;
    };

    // Start the HBM stream first.
    f32x4 m1 = loadrow(t0 + 1);
    f32x4 m2 = loadrow(t0 + 2);
    f32x4 m3 = loadrow(t0 + 3);

    // Coalesced span preload: lane i (i<TC) holds spans[b, t0+i].
    int myspan = 0;
    if (lane < TC) myspan = spans[b * SS + t0 + lane];

    // mask_len[b] = sum(masks[b,:]) — fused per-block reduce (2 KB, cache-hot).
    int msum = 0;
    const int* mrow = masks + b * SS;
    #pragma unroll
    for (int i = 0; i < SS / 64; ++i) msum += mrow[lane + i * 64];
    #pragma unroll
    for (int off = 32; off; off >>= 1) msum += __shfl_down(msum, off, 64);
    const int ml = __shfl(msum, 0, 64);

    f32x4* orow = (f32x4*)out + ((size_t)b * SS + t0) * H4 + col;

    #pragma unroll 4
    for (int i = 0; i < TC; ++i) {
        const int t = t0 + i;
        f32x4 nxt = loadrow(t + 4);              // prefetch next window row
        const int span_i = __shfl(myspan, i, 64);
        const bool valid = (t >= 1) && (t < ml - 1);
        const int n = min(span_i, SS - 1 - t);   // 1..3 when valid
        const float w1 = valid ? 0.25f : 0.0f;
        const float w2 = (valid && n >= 2) ? 0.25f : 0.0f;
        const float w3 = (valid && n >= 3) ? 0.25f : 0.0f;
        f32x4 r = w1 * m1 + w2 * m2 + w3 * m3;
        orow[(size_t)i * H4] = r;
        m1 = m2; m2 = m3; m3 = nxt;
    }
}

extern "C" void kernel_launch(void* const* d_in, const int* in_sizes, int n_in,
                              void* d_out, int out_size, void* d_ws, size_t ws_size,
                              hipStream_t stream) {
    const float* hidden = (const float*)d_in[0];  // [4,B,S,H] f32
    const int* spans    = (const int*)d_in[1];    // [B,S] i32
    const int* masks    = (const int*)d_in[2];    // [B,S] i32
    float* out          = (float*)d_out;          // [B,S,H] f32

    dim3 grid(NSC, NHS, BB);  // 16 x 3 x 16 = 768 single-wave blocks
    span_pool_kernel<<<grid, dim3(64), 0, stream>>>(hidden, spans, masks, out);
}